// Round 7
// baseline (2888.068 us; speedup 1.0000x reference)
//
#include <hip/hip_runtime.h>
#include <math.h>

#define T_LEN 8192
#define NUM_CH 64
#define HID 256
#define NUM_CLS 40
#define NUM_PROP 1024
#define NUM_PROP_AFTER 256
#define PROP_LEN 128

#define KH 320        // block-local K order: [0,128) own-h, [128,192) x, [192,320) peer-h
#define HXPAR 65536   // u32 per parity buffer: 256 seqs x 256 units

typedef _Float16 h2_t __attribute__((ext_vector_type(2)));
union U32H2 { unsigned int u; h2_t h; };
union HU16 { _Float16 h; unsigned short u; };

#if defined(__has_builtin)
#if __has_builtin(__builtin_amdgcn_fdot2)
#define HAS_FDOT2 1
#endif
#endif

__device__ __forceinline__ float dot2f(unsigned int wa, unsigned int hb, float acc) {
    U32H2 a, b;
    a.u = wa;
    b.u = hb;
#ifdef HAS_FDOT2
    return __builtin_amdgcn_fdot2(a.h, b.h, acc, false);
#else
    return acc + (float)a.h[0] * (float)b.h[0] + (float)a.h[1] * (float)b.h[1];
#endif
}

__device__ __forceinline__ float dot8f(const uint4& w, const uint4& h, float acc) {
    acc = dot2f(w.x, h.x, acc);
    acc = dot2f(w.y, h.y, acc);
    acc = dot2f(w.z, h.z, acc);
    acc = dot2f(w.w, h.w, acc);
    return acc;
}

__device__ __forceinline__ float fsigmoid(float x) { return 1.0f / (1.0f + __expf(-x)); }
__device__ __forceinline__ float ftanh(float x) {
    float e = __expf(-2.0f * fabsf(x));
    float t = (1.0f - e) / (1.0f + e);
    return copysignf(t, x);
}

__device__ __forceinline__ unsigned int pack2(float a, float b) {
    HU16 ha, hb;
    ha.h = (_Float16)a;
    hb.h = (_Float16)b;
    return (unsigned int)ha.u | ((unsigned int)hb.u << 16);
}

// ---------------------------------------------------------------------------
// 256 blocks = 128 groups (2 seqs) x 2 hidden slices (128 units).
// Pair blocks are b and b+8 (same XCD under round-robin dispatch).
// Thread = (kseg = tid>>9, row = tid&511); W frag = 20 uint4 (160 f16) in
// block-local K order: kseg0 covers k[0,160) = all LOCAL (own-h + x[0,32));
// kseg1 covers k[160,320) = x[32,64) local + k[192,320) PEER.
// Per step: W1 { kseg0: full dot; waves 6-7 also gather peer-h (arrive-late
// global tag-loads -> LDS + flag); kseg1: local dot, LDS-flag wait, peer dot }
// barrier; W2 { waves 0-3: reduce+act+tagged-publish+own-h LDS; waves 4-5:
// x(t+1) reg->LDS } barrier.  One peer, 256 exchange words, 2 barriers.
// ---------------------------------------------------------------------------
__global__ __launch_bounds__(1024, 4) void fused_kernel(
    const float* __restrict__ data, const float* __restrict__ prop,
    const float* __restrict__ W_ih, const float* __restrict__ W_hh,
    const float* __restrict__ b_ih, const float* __restrict__ b_hh,
    const float* __restrict__ W_cls, const float* __restrict__ b_cls,
    const float* __restrict__ W_bbox, const float* __restrict__ b_bbox,
    float* __restrict__ out, unsigned int* __restrict__ t0s,
    unsigned int* __restrict__ Hx32) {
    __shared__ __align__(16) unsigned char smem[13568];

    const int tid = threadIdx.x;
    const int bidx = blockIdx.x;
    const int s = (bidx >> 3) & 1;                    // hidden slice
    const int p = (bidx & 7) | ((bidx >> 4) << 3);    // group (pair id), co-XCD
    const int kseg = tid >> 9;                        // wave-uniform
    const int row = tid & 511;                        // gate*128 + unit
    const int wid = tid >> 6;

    float* pp = (float*)smem;                                  // [2 sq][2 ks][512] 8KB
    _Float16* hx = (_Float16*)(smem + 8192);                   // [2 sq][KH] 1.28KB
    volatile unsigned int* gf = (volatile unsigned int*)(smem + 8192 + 1280);

    // ===================== block 0: NMS (smem overlay) =====================
    if (bidx == 0) {
        float* sc_p = (float*)smem;
        float* ss = (float*)(smem + 4096);
        float* se = (float*)(smem + 8192);
        unsigned char* sup = smem + 12288;
        unsigned long long* cmask = (unsigned long long*)(smem + 13312);

        float ps = prop[tid * 3 + 0];
        float pe = prop[tid * 3 + 1];
        float pc = prop[tid * 3 + 2];
        sc_p[tid] = pc;
        sup[tid] = 0;
        __syncthreads();

        int r = 0;
        for (int j = 0; j < NUM_PROP; ++j) {
            float o = sc_p[j];
            r += (o > pc) || (o == pc && j < tid);
        }
        ss[r] = ps;
        se[r] = pe;
        __syncthreads();

        const float my_s = ss[tid];
        const float my_e = se[tid];
        const float my_len = my_e - my_s;
        bool mysup = false;

        for (int ci = 0; ci < 16; ++ci) {
            if (tid < 64) {
                int i = ci * 64 + tid;
                float is_ = ss[i], ie_ = se[i];
                unsigned long long m = __ballot(sup[i] != 0);
                for (int l = 0; l < 64; ++l) {
                    if (!((m >> l) & 1)) {
                        float ls = __shfl(is_, l);
                        float le = __shfl(ie_, l);
                        float inter = fmaxf(fminf(le, ie_) - fmaxf(ls, is_), 0.0f);
                        float uni = (le - ls) + (ie_ - is_) - inter;
                        float iou = inter / fmaxf(uni, 1e-6f);
                        unsigned long long nb2 = __ballot((tid > l) && (iou > 0.5f));
                        m |= nb2;
                    }
                }
                sup[i] = (unsigned char)((m >> tid) & 1);
                if (tid == 0) cmask[ci] = ~m;
            }
            __syncthreads();
            unsigned long long am = cmask[ci];
            for (int l = 0; l < 64; ++l) {
                if ((am >> l) & 1) {
                    int i = ci * 64 + l;
                    if (tid > i && !mysup) {
                        float ls = ss[i], le = se[i];
                        float inter = fmaxf(fminf(le, my_e) - fmaxf(ls, my_s), 0.0f);
                        float uni = (le - ls) + my_len - inter;
                        if (inter / fmaxf(uni, 1e-6f) > 0.5f) mysup = true;
                    }
                }
            }
            sup[tid] = mysup ? 1 : 0;
            __syncthreads();
        }

        int myc = tid >> 6;
        unsigned long long mybit = 1ull << (tid & 63);
        int kb = 0, kt = 0;
        for (int c2 = 0; c2 < 16; ++c2) {
            int pc2 = __popcll(cmask[c2]);
            kt += pc2;
            if (c2 < myc) kb += pc2;
        }
        kb += __popcll(cmask[myc] & (mybit - 1));
        int slot = (cmask[myc] & mybit) ? kb : (kt + (tid - kb));
        if (slot < NUM_PROP_AFTER) {
            int t0v = (int)rintf(my_s);
            t0v = max(0, min(t0v, T_LEN - PROP_LEN));
            __hip_atomic_store(&t0s[slot], (unsigned int)t0v | 0x80000000u,
                               __ATOMIC_RELAXED, __HIP_MEMORY_SCOPE_AGENT);
        }
        asm volatile("s_waitcnt vmcnt(0)" ::: "memory");
        __syncthreads();
    }

    // ============ W fragment: 20 uint4 in block-local K order ============
    uint4 Wr[20];
    {
        const int gate = row >> 7, unit = row & 127;
        const int grow = gate * 256 + s * 128 + unit;
        const float* __restrict__ bh = W_hh + grow * HID;
        const float* __restrict__ bx = W_ih + grow * NUM_CH;
#pragma unroll
        for (int j = 0; j < 20; ++j) {
            const int kp = kseg * 160 + j * 8;  // block-local kappa
            const float* src;
            if (kp < 128) src = bh + s * 128 + kp;              // own-slice h
            else if (kp < 192) src = bx + (kp - 128);           // x
            else src = bh + (1 - s) * 128 + (kp - 192);         // peer-slice h
            float4 f0 = *(const float4*)src;
            float4 f1 = *(const float4*)(src + 4);
            Wr[j] = make_uint4(pack2(f0.x, f0.y), pack2(f0.z, f0.w),
                               pack2(f1.x, f1.y), pack2(f1.z, f1.w));
        }
    }

    // reducer role (waves 0-3): (sqr = tid>>7, ur = tid&127)
    const int sqr = tid >> 7;
    const int ur = tid & 127;
    float bi = 0.f, bf = 0.f, bg = 0.f, bo = 0.f, c_st = 0.f;
    if (tid < 256) {
        int gu = s * 128 + ur;
        bi = b_ih[gu] + b_hh[gu];
        bf = b_ih[256 + gu] + b_hh[256 + gu];
        bg = b_ih[512 + gu] + b_hh[512 + gu];
        bo = b_ih[768 + gu] + b_hh[768 + gu];
    }

    // init LDS: zero hx (640 halves), flags
    if (tid < 640) ((unsigned short*)hx)[tid] = 0;
    if (tid == 0) { gf[0] = 0; gf[1] = 0; }
    __syncthreads();

    // x role (waves 4-5): seq sqx, channel chx; poll tagged t0s
    const int sqx = (tid >> 6) & 1;
    const int chx = tid & 63;
    int xt0 = 0;
    if (wid == 4 || wid == 5) {
        const unsigned int* tp = &t0s[2 * p + sqx];
        unsigned int tv;
        for (;;) {
            tv = __hip_atomic_load(tp, __ATOMIC_RELAXED, __HIP_MEMORY_SCOPE_AGENT);
            if (tv & 0x80000000u) break;
            __builtin_amdgcn_s_sleep(8);
        }
        xt0 = (int)(tv & 0x7FFFFFFFu);
        hx[sqx * KH + 128 + chx] = (_Float16)data[xt0 * NUM_CH + chx];  // x(0)
    }
    __syncthreads();

    // gather constants (waves 6-7): lane li covers (sq0,li) and (sq1,li)
    const int li = tid - 384;  // 0..127 for waves 6-7
    const int peerbase = 2 * p * 256 + (1 - s) * 128;

    for (int t = 0; t < PROP_LEN; ++t) {
        float a0 = 0.f, a1 = 0.f;
        // early x(t+1) issue (waves 4-5); lands during dot
        float xreg = 0.f;
        if ((wid == 4 || wid == 5) && t + 1 < PROP_LEN)
            xreg = data[(xt0 + t + 1) * NUM_CH + chx];

        if (kseg == 0) {
            // --- fully local dot: kappa [0,160) ---
#pragma unroll
            for (int j = 0; j < 20; ++j) {
                uint4 h0 = *(const uint4*)(hx + 0 * KH + j * 8);
                uint4 h1 = *(const uint4*)(hx + 1 * KH + j * 8);
                a0 = dot8f(Wr[j], h0, a0);
                a1 = dot8f(Wr[j], h1, a1);
            }
            // --- gather waves: fetch peer h(t) (published in peer's W2(t-1)) ---
            if ((wid == 6 || wid == 7) && t >= 1) {
                const int par = t & 1;
                const unsigned int tag = (unsigned int)t;
                const unsigned int* q0 = Hx32 + par * HXPAR + peerbase + li;
                const unsigned int* q1 = q0 + 256;  // seq 1
                unsigned int v0 = 0, v1 = 0;
                bool d0 = false, d1 = false;
                for (;;) {
                    if (!d0) {
                        v0 = __hip_atomic_load(q0, __ATOMIC_RELAXED,
                                               __HIP_MEMORY_SCOPE_AGENT);
                        d0 = (v0 >> 16) == tag;
                    }
                    if (!d1) {
                        v1 = __hip_atomic_load(q1, __ATOMIC_RELAXED,
                                               __HIP_MEMORY_SCOPE_AGENT);
                        d1 = (v1 >> 16) == tag;
                    }
                    if (d0 && d1) break;
                    __builtin_amdgcn_s_sleep(1);
                }
                HU16 h0v, h1v;
                h0v.u = (unsigned short)(v0 & 0xFFFFu);
                h1v.u = (unsigned short)(v1 & 0xFFFFu);
                hx[0 * KH + 192 + li] = h0v.h;
                hx[1 * KH + 192 + li] = h1v.h;
                asm volatile("s_waitcnt lgkmcnt(0)" ::: "memory");
                if ((tid & 63) == 0) gf[wid - 6] = (unsigned int)t;
            }
        } else {
            // --- local tail: kappa [160,192) = x[32,64) ---
#pragma unroll
            for (int j = 0; j < 4; ++j) {
                uint4 h0 = *(const uint4*)(hx + 0 * KH + 160 + j * 8);
                uint4 h1 = *(const uint4*)(hx + 1 * KH + 160 + j * 8);
                a0 = dot8f(Wr[j], h0, a0);
                a1 = dot8f(Wr[j], h1, a1);
            }
            // --- wait for peer-h in LDS (flag = t) ---
            while (gf[0] < (unsigned int)t || gf[1] < (unsigned int)t) {
                __builtin_amdgcn_s_sleep(1);
            }
            asm volatile("" ::: "memory");
            // --- peer dot: kappa [192,320) ---
#pragma unroll
            for (int j = 4; j < 20; ++j) {
                uint4 h0 = *(const uint4*)(hx + 0 * KH + 160 + j * 8);
                uint4 h1 = *(const uint4*)(hx + 1 * KH + 160 + j * 8);
                a0 = dot8f(Wr[j], h0, a0);
                a1 = dot8f(Wr[j], h1, a1);
            }
        }
        pp[(0 * 2 + kseg) * 512 + row] = a0;
        pp[(1 * 2 + kseg) * 512 + row] = a1;
        __syncthreads();

        // ------------------------------ W2 ------------------------------
        const unsigned int tag2 = (unsigned int)(t + 1);
        const int par2 = (t + 1) & 1;
        if (tid < 256) {
            float si = pp[(sqr * 2 + 0) * 512 + ur] + pp[(sqr * 2 + 1) * 512 + ur] + bi;
            float sf = pp[(sqr * 2 + 0) * 512 + 128 + ur] +
                       pp[(sqr * 2 + 1) * 512 + 128 + ur] + bf;
            float sg = pp[(sqr * 2 + 0) * 512 + 256 + ur] +
                       pp[(sqr * 2 + 1) * 512 + 256 + ur] + bg;
            float so = pp[(sqr * 2 + 0) * 512 + 384 + ur] +
                       pp[(sqr * 2 + 1) * 512 + 384 + ur] + bo;
            float gi = fsigmoid(si), gff = fsigmoid(sf);
            float gg = ftanh(sg), go = fsigmoid(so);
            c_st = gff * c_st + gi * gg;
            float h = go * ftanh(c_st);
            HU16 hu;
            hu.h = (_Float16)h;
            __hip_atomic_store(
                &Hx32[par2 * HXPAR + (2 * p + sqr) * 256 + s * 128 + ur],
                (tag2 << 16) | (unsigned int)hu.u, __ATOMIC_RELAXED,
                __HIP_MEMORY_SCOPE_AGENT);
            hx[sqr * KH + ur] = hu.h;  // own slice, local kappa = ur
        } else if (wid == 4 || wid == 5) {
            if (t + 1 < PROP_LEN) hx[sqx * KH + 128 + chx] = (_Float16)xreg;
        }
        __syncthreads();
    }

    // final gather: peer h(128) (tag 128, parity 0) for the heads
    if (wid == 6 || wid == 7) {
        const unsigned int tag = (unsigned int)PROP_LEN;
        const unsigned int* q0 = Hx32 + 0 * HXPAR + peerbase + li;
        const unsigned int* q1 = q0 + 256;
        unsigned int v0 = 0, v1 = 0;
        bool d0 = false, d1 = false;
        for (;;) {
            if (!d0) {
                v0 = __hip_atomic_load(q0, __ATOMIC_RELAXED, __HIP_MEMORY_SCOPE_AGENT);
                d0 = (v0 >> 16) == tag;
            }
            if (!d1) {
                v1 = __hip_atomic_load(q1, __ATOMIC_RELAXED, __HIP_MEMORY_SCOPE_AGENT);
                d1 = (v1 >> 16) == tag;
            }
            if (d0 && d1) break;
            __builtin_amdgcn_s_sleep(1);
        }
        HU16 h0v, h1v;
        h0v.u = (unsigned short)(v0 & 0xFFFFu);
        h1v.u = (unsigned short)(v1 & 0xFFFFu);
        hx[0 * KH + 192 + li] = h0v.h;
        hx[1 * KH + 192 + li] = h1v.h;
    }
    __syncthreads();

    // heads: 2 seqs x 60 rows (slice s covers m in [60s, 60s+60))
    if (tid < 120) {
        int sq = tid / 60;
        int mi = tid % 60;
        int m = s * 60 + mi;
        int seqg = 2 * p + sq;
        const float* Wrow;
        float acc;
        int oidx;
        if (m < NUM_CLS) {
            Wrow = W_cls + m * HID;
            acc = b_cls[m];
            oidx = seqg * NUM_CLS + m;
        } else {
            int mb = m - NUM_CLS;
            Wrow = W_bbox + mb * HID;
            acc = b_bbox[mb];
            oidx = NUM_PROP_AFTER * NUM_CLS + seqg * 2 * NUM_CLS + mb;
        }
        for (int k = 0; k < 128; ++k)
            acc += Wrow[s * 128 + k] * (float)hx[sq * KH + k];
        for (int k = 0; k < 128; ++k)
            acc += Wrow[(1 - s) * 128 + k] * (float)hx[sq * KH + 192 + k];
        out[oidx] = acc;
    }
}

extern "C" void kernel_launch(void* const* d_in, const int* in_sizes, int n_in,
                              void* d_out, int out_size, void* d_ws,
                              size_t ws_size, hipStream_t stream) {
    const float* data = (const float*)d_in[0];     // [8192, 64]
    const float* prop = (const float*)d_in[1];     // [1024, 3]
    const float* W_ih = (const float*)d_in[2];     // [1024, 64]
    const float* W_hh = (const float*)d_in[3];     // [1024, 256]
    const float* b_ih = (const float*)d_in[4];     // [1024]
    const float* b_hh = (const float*)d_in[5];     // [1024]
    const float* W_cls = (const float*)d_in[6];    // [40, 256]
    const float* b_cls = (const float*)d_in[7];    // [40]
    const float* W_bbox = (const float*)d_in[8];   // [80, 256]
    const float* b_bbox = (const float*)d_in[9];   // [80]
    float* out = (float*)d_out;

    // workspace layout
    unsigned int* t0s = (unsigned int*)d_ws;                   // [0, 1KB) tagged t0s
    unsigned int* Hx32 = (unsigned int*)((char*)d_ws + 4096);  // 512 KB tagged h (2 parities)

    // zero all tags each invocation (graph-captured, replayed per rep)
    hipMemsetAsync(d_ws, 0, 4096 + 2 * HXPAR * 4, stream);

    void* kargs[] = {(void*)&data,  (void*)&prop,   (void*)&W_ih,  (void*)&W_hh,
                     (void*)&b_ih,  (void*)&b_hh,   (void*)&W_cls, (void*)&b_cls,
                     (void*)&W_bbox, (void*)&b_bbox, (void*)&out,  (void*)&t0s,
                     (void*)&Hx32};
    hipLaunchCooperativeKernel((void*)fused_kernel, dim3(256), dim3(1024),
                               kargs, 0, stream);
}

// Round 9
// 799.760 us; speedup vs baseline: 3.6112x; 3.6112x over previous
//
#include <hip/hip_runtime.h>
#include <math.h>

#define T_LEN 8192
#define NUM_CH 64
#define HID 256
#define NUM_CLS 40
#define NUM_PROP 1024
#define NUM_PROP_AFTER 256
#define PROP_LEN 128

#define MS 4        // sequences per group
#define NGRP 64     // sequence groups (NUM_PROP_AFTER / MS)
#define NSL 4       // hidden slices (64 units each)
#define KH 320      // K in halves: 256 h + 64 x
#define KSEGN 4     // K segments per row
#define SEGH 80     // halves per segment
#define HXPAR 65536 // u32s per parity buffer: 256 seqs x 256 units

typedef _Float16 h2_t __attribute__((ext_vector_type(2)));
union U32H2 { unsigned int u; h2_t h; };
union HU16 { _Float16 h; unsigned short u; };

#if defined(__has_builtin)
#if __has_builtin(__builtin_amdgcn_fdot2)
#define HAS_FDOT2 1
#endif
#endif

__device__ __forceinline__ float dot2f(unsigned int wa, unsigned int hb, float acc) {
    U32H2 a, b;
    a.u = wa;
    b.u = hb;
#ifdef HAS_FDOT2
    return __builtin_amdgcn_fdot2(a.h, b.h, acc, false);
#else
    return acc + (float)a.h[0] * (float)b.h[0] + (float)a.h[1] * (float)b.h[1];
#endif
}

__device__ __forceinline__ float dot8f(const uint4& w, const uint4& h, float acc) {
    acc = dot2f(w.x, h.x, acc);
    acc = dot2f(w.y, h.y, acc);
    acc = dot2f(w.z, h.z, acc);
    acc = dot2f(w.w, h.w, acc);
    return acc;
}

__device__ __forceinline__ float fsigmoid(float x) { return 1.0f / (1.0f + __expf(-x)); }
__device__ __forceinline__ float ftanh(float x) {
    float e = __expf(-2.0f * fabsf(x));
    float t = (1.0f - e) / (1.0f + e);
    return copysignf(t, x);
}

__device__ __forceinline__ unsigned int pack2(float a, float b) {
    HU16 ha, hb;
    ha.h = (_Float16)a;
    hb.h = (_Float16)b;
    return (unsigned int)ha.u | ((unsigned int)hb.u << 16);
}

// ---------------------------------------------------------------------------
// Fused cooperative kernel: 256 blocks (4 hid-slices x 64 seq-groups).
// EXCHANGE PROTOCOL (sound-by-construction, R5-verified, + R2-speed hint):
//  - each h published as tagged u32 (tag=t+1 <<16 | f16), parity dbuf.
//  - producers drain (vmcnt 0) then fetch_add a per-group HINT counter.
//  - ONE lane sleep-polls the hint; after a barrier the 768 gather threads
//    load their word and VALIDATE THE TAG (retry loop). Correctness never
//    depends on the hint/counter ordering -- the tag is the guarantee; the
//    hint only prevents 768-lane polling storms (R5's congestion).
// Roles/step: all 16 waves dot | B1 | waves 0-3 reduce+act+publish+LDS(own h,
// x) +drain+hint-add; tid256 polls hint | B2 | tid>=256 gather tagged words
// | B3.  x(t+1) early-issued by producers before the dot.
// ---------------------------------------------------------------------------
__global__ __launch_bounds__(1024, 4) void fused_kernel(
    const float* __restrict__ data, const float* __restrict__ prop,
    const float* __restrict__ W_ih, const float* __restrict__ W_hh,
    const float* __restrict__ b_ih, const float* __restrict__ b_hh,
    const float* __restrict__ W_cls, const float* __restrict__ b_cls,
    const float* __restrict__ W_bbox, const float* __restrict__ b_bbox,
    float* __restrict__ out, unsigned int* __restrict__ t0s,
    unsigned int* __restrict__ Hx32, unsigned int* __restrict__ cnt) {
    __shared__ __align__(16) _Float16 hx[MS][KH];       // 2.5 KB
    __shared__ __align__(16) float pp[MS][KSEGN][256];  // 16 KB (NMS overlay)

    const int tid = threadIdx.x;
    const int g = blockIdx.x & (NGRP - 1);
    const int s = blockIdx.x >> 6;
    const int kseg = tid >> 8;   // wave-uniform K segment
    const int rl = tid & 255;    // row_local = gate*64 + unit

    // ===================== block 0: NMS =====================
    if (blockIdx.x == 0) {
        float* sc_p = &pp[0][0][0];
        float* ss = &pp[1][0][0];
        float* se = &pp[2][0][0];
        unsigned char* sup = (unsigned char*)&pp[3][0][0];
        unsigned long long* cmask =
            (unsigned long long*)((char*)&pp[3][0][0] + 1024);

        float ps = prop[tid * 3 + 0];
        float pe = prop[tid * 3 + 1];
        float pc = prop[tid * 3 + 2];
        sc_p[tid] = pc;
        sup[tid] = 0;
        __syncthreads();

        int r = 0;
        for (int j = 0; j < NUM_PROP; ++j) {
            float o = sc_p[j];
            r += (o > pc) || (o == pc && j < tid);
        }
        ss[r] = ps;
        se[r] = pe;
        __syncthreads();

        const float my_s = ss[tid];
        const float my_e = se[tid];
        const float my_len = my_e - my_s;
        bool mysup = false;

        for (int ci = 0; ci < 16; ++ci) {
            if (tid < 64) {
                int i = ci * 64 + tid;
                float is_ = ss[i], ie_ = se[i];
                unsigned long long m = __ballot(sup[i] != 0);
                for (int l = 0; l < 64; ++l) {
                    if (!((m >> l) & 1)) {
                        float ls = __shfl(is_, l);
                        float le = __shfl(ie_, l);
                        float inter = fmaxf(fminf(le, ie_) - fmaxf(ls, is_), 0.0f);
                        float uni = (le - ls) + (ie_ - is_) - inter;
                        float iou = inter / fmaxf(uni, 1e-6f);
                        unsigned long long nb = __ballot((tid > l) && (iou > 0.5f));
                        m |= nb;
                    }
                }
                sup[i] = (unsigned char)((m >> tid) & 1);
                if (tid == 0) cmask[ci] = ~m;
            }
            __syncthreads();
            unsigned long long am = cmask[ci];
            for (int l = 0; l < 64; ++l) {
                if ((am >> l) & 1) {
                    int i = ci * 64 + l;
                    if (tid > i && !mysup) {
                        float ls = ss[i], le = se[i];
                        float inter = fmaxf(fminf(le, my_e) - fmaxf(ls, my_s), 0.0f);
                        float uni = (le - ls) + my_len - inter;
                        if (inter / fmaxf(uni, 1e-6f) > 0.5f) mysup = true;
                    }
                }
            }
            sup[tid] = mysup ? 1 : 0;
            __syncthreads();
        }

        int myc = tid >> 6;
        unsigned long long mybit = 1ull << (tid & 63);
        int kb = 0, kt = 0;
        for (int c2 = 0; c2 < 16; ++c2) {
            int p = __popcll(cmask[c2]);
            kt += p;
            if (c2 < myc) kb += p;
        }
        kb += __popcll(cmask[myc] & (mybit - 1));
        int slot = (cmask[myc] & mybit) ? kb : (kt + (tid - kb));
        if (slot < NUM_PROP_AFTER) {
            int t0v = (int)rintf(my_s);
            t0v = max(0, min(t0v, T_LEN - PROP_LEN));
            __hip_atomic_store(&t0s[slot], (unsigned int)t0v | 0x80000000u,
                               __ATOMIC_RELAXED, __HIP_MEMORY_SCOPE_AGENT);
        }
        asm volatile("s_waitcnt vmcnt(0)" ::: "memory");
        __syncthreads();
    }

    // ============ W fragment: direct f32 load + f16 pack ============
    uint4 Wr[10];
    {
        const int gate = rl >> 6, unit = rl & 63;
        const int grow = gate * 256 + s * 64 + unit;
        const float* __restrict__ baseh = W_hh + grow * HID;
        const float* __restrict__ basex = W_ih + grow * NUM_CH;
#pragma unroll
        for (int j = 0; j < 10; ++j) {
            const int kh = kseg * SEGH + j * 8;
            const float* src = (kh < 256) ? (baseh + kh) : (basex + (kh - 256));
            float4 f0 = *(const float4*)(src);
            float4 f1 = *(const float4*)(src + 4);
            Wr[j] = make_uint4(pack2(f0.x, f0.y), pack2(f0.z, f0.w),
                               pack2(f1.x, f1.y), pack2(f1.z, f1.w));
        }
    }

    // producer role (tid<256): wave aq = seq, lane au = unit of slice s
    const int aq = tid >> 6;
    const int au = tid & 63;
    float bi = 0.f, bf = 0.f, bg = 0.f, bo = 0.f, c_st = 0.f;
    int xt0 = 0;
    if (tid < 256) {
        int u = s * 64 + au;
        bi = b_ih[u] + b_hh[u];
        bf = b_ih[256 + u] + b_hh[256 + u];
        bg = b_ih[512 + u] + b_hh[512 + u];
        bo = b_ih[768 + u] + b_hh[768 + u];
    }

    // gather role (tid>=256): word (peer slice sp, seq gsq, unit gu)
    const int tid2 = tid - 256;          // 0..767
    const int gp = tid2 >> 8;            // 0..2 peer index
    const int gr = tid2 & 255;
    const int gsq = gr >> 6, gu = gr & 63;
    const int sp = gp + (gp >= s ? 1 : 0);
    const unsigned int* gaddr = Hx32 + (g * MS + gsq) * HID + sp * 64 + gu;

    unsigned int* cg = &cnt[g * 16];  // one 64B line per group (hint)

    // zero h region of hx
    hx[tid >> 8][tid & 255] = (_Float16)0.0f;

    // producers poll tagged t0s (64 lanes same addr, s_sleep backoff), load x(0)
    if (tid < 256) {
        const unsigned int* tp = &t0s[g * MS + aq];
        unsigned int tv;
        for (;;) {
            tv = __hip_atomic_load(tp, __ATOMIC_RELAXED, __HIP_MEMORY_SCOPE_AGENT);
            if (tv & 0x80000000u) break;
            __builtin_amdgcn_s_sleep(8);
        }
        xt0 = (int)(tv & 0x7FFFFFFFu);
        hx[aq][256 + au] = (_Float16)data[xt0 * NUM_CH + au];  // x(0)
    }
    __syncthreads();

    for (int t = 0; t < PROP_LEN; ++t) {
        // producers: issue x(t+1) load EARLY (consumed after the dot; HBM
        // latency hides under the ~1.3us dot)
        float xnext = 0.0f;
        if (tid < 256 && t + 1 < PROP_LEN)
            xnext = data[(xt0 + t + 1) * NUM_CH + au];

        // --- dot: 4 accumulator chains, broadcast LDS reads ---
        float a0 = 0.f, a1 = 0.f, a2 = 0.f, a3 = 0.f;
#pragma unroll
        for (int j = 0; j < 10; ++j) {
            const int hb = kseg * SEGH + j * 8;
            uint4 h0 = *(const uint4*)&hx[0][hb];
            uint4 h1 = *(const uint4*)&hx[1][hb];
            uint4 h2 = *(const uint4*)&hx[2][hb];
            uint4 h3 = *(const uint4*)&hx[3][hb];
            uint4 w = Wr[j];
            a0 = dot8f(w, h0, a0);
            a1 = dot8f(w, h1, a1);
            a2 = dot8f(w, h2, a2);
            a3 = dot8f(w, h3, a3);
        }
        pp[0][kseg][rl] = a0;
        pp[1][kseg][rl] = a1;
        pp[2][kseg][rl] = a2;
        pp[3][kseg][rl] = a3;
        __syncthreads();  // B1

        const unsigned int tagv = (unsigned int)(t + 1);
        const int par = (t + 1) & 1;
        if (tid < 256) {
            // --- reduce + activation + tagged publish + local LDS writes ---
            float si = pp[aq][0][au] + pp[aq][1][au] + pp[aq][2][au] +
                       pp[aq][3][au] + bi;
            float sf = pp[aq][0][64 + au] + pp[aq][1][64 + au] +
                       pp[aq][2][64 + au] + pp[aq][3][64 + au] + bf;
            float sg = pp[aq][0][128 + au] + pp[aq][1][128 + au] +
                       pp[aq][2][128 + au] + pp[aq][3][128 + au] + bg;
            float so = pp[aq][0][192 + au] + pp[aq][1][192 + au] +
                       pp[aq][2][192 + au] + pp[aq][3][192 + au] + bo;
            float gi = fsigmoid(si), gf = fsigmoid(sf);
            float gg = ftanh(sg), go = fsigmoid(so);
            c_st = gf * c_st + gi * gg;
            float h = go * ftanh(c_st);
            HU16 hu;
            hu.h = (_Float16)h;
            __hip_atomic_store(
                &Hx32[par * HXPAR + (g * MS + aq) * HID + s * 64 + au],
                (tagv << 16) | (unsigned int)hu.u, __ATOMIC_RELAXED,
                __HIP_MEMORY_SCOPE_AGENT);
            hx[aq][s * 64 + au] = hu.h;                       // own slice -> LDS
            if (t + 1 < PROP_LEN) hx[aq][256 + au] = (_Float16)xnext;  // x(t+1)
            // drain: publish acked before the hint add (makes hint conservative)
            asm volatile("s_waitcnt vmcnt(0)" ::: "memory");
            if (au == 0)
                __hip_atomic_fetch_add(cg, 1u, __ATOMIC_RELAXED,
                                       __HIP_MEMORY_SCOPE_AGENT);
        } else if (tid == 256) {
            // --- single quiet poller on the hint counter ---
            const unsigned int tgt = 16u * tagv;
            while (__hip_atomic_load(cg, __ATOMIC_RELAXED,
                                     __HIP_MEMORY_SCOPE_AGENT) < tgt) {
                __builtin_amdgcn_s_sleep(1);
            }
        }
        __syncthreads();  // B2: hint passed -> gathers begin

        if (tid >= 256) {
            // --- gather tagged word; TAG VALIDATION is the correctness gate ---
            const unsigned int* ga = gaddr + par * HXPAR;
            unsigned int v =
                __hip_atomic_load(ga, __ATOMIC_RELAXED, __HIP_MEMORY_SCOPE_AGENT);
            while (__builtin_expect((v >> 16) != tagv, 0)) {
                __builtin_amdgcn_s_sleep(1);
                v = __hip_atomic_load(ga, __ATOMIC_RELAXED,
                                      __HIP_MEMORY_SCOPE_AGENT);
            }
            HU16 hv;
            hv.u = (unsigned short)(v & 0xFFFFu);
            hx[gsq][sp * 64 + gu] = hv.h;
        }
        __syncthreads();  // B3
    }

    // hx holds h_128 for all 4 seqs. Slice s computes rows [30s, 30s+30).
    if (tid < MS * 30) {
        int sq = tid / 30;
        int ml = tid % 30;
        int m = s * 30 + ml;
        const float* Wrow;
        float acc;
        int oidx;
        if (m < NUM_CLS) {
            Wrow = W_cls + m * HID;
            acc = b_cls[m];
            oidx = (g * MS + sq) * NUM_CLS + m;
        } else {
            int mb = m - NUM_CLS;
            Wrow = W_bbox + mb * HID;
            acc = b_bbox[mb];
            oidx = NUM_PROP_AFTER * NUM_CLS + (g * MS + sq) * 2 * NUM_CLS + mb;
        }
        const float4* w4 = (const float4*)Wrow;
        const _Float16* hp = &hx[sq][0];
        for (int c = 0; c < 32; ++c) {
            float4 wa = w4[c * 2 + 0];
            float4 wb = w4[c * 2 + 1];
            acc += (float)hp[c * 8 + 0] * wa.x + (float)hp[c * 8 + 1] * wa.y +
                   (float)hp[c * 8 + 2] * wa.z + (float)hp[c * 8 + 3] * wa.w +
                   (float)hp[c * 8 + 4] * wb.x + (float)hp[c * 8 + 5] * wb.y +
                   (float)hp[c * 8 + 6] * wb.z + (float)hp[c * 8 + 7] * wb.w;
        }
        out[oidx] = acc;
    }
}

extern "C" void kernel_launch(void* const* d_in, const int* in_sizes, int n_in,
                              void* d_out, int out_size, void* d_ws,
                              size_t ws_size, hipStream_t stream) {
    const float* data = (const float*)d_in[0];     // [8192, 64]
    const float* prop = (const float*)d_in[1];     // [1024, 3]
    const float* W_ih = (const float*)d_in[2];     // [1024, 64]
    const float* W_hh = (const float*)d_in[3];     // [1024, 256]
    const float* b_ih = (const float*)d_in[4];     // [1024]
    const float* b_hh = (const float*)d_in[5];     // [1024]
    const float* W_cls = (const float*)d_in[6];    // [40, 256]
    const float* b_cls = (const float*)d_in[7];    // [40]
    const float* W_bbox = (const float*)d_in[8];   // [80, 256]
    const float* b_bbox = (const float*)d_in[9];   // [80]
    float* out = (float*)d_out;

    // workspace layout
    unsigned int* t0s = (unsigned int*)d_ws;                    // [0,1KB) tagged t0s
    unsigned int* cnt = (unsigned int*)((char*)d_ws + 1024);    // [1KB,5KB) hint counters
    unsigned int* Hx32 = (unsigned int*)((char*)d_ws + 8192);   // 512KB tagged h (2 parities)

    // zero tags + counters each invocation (graph-captured, replayed per rep)
    hipMemsetAsync(d_ws, 0, 8192 + 2 * HXPAR * 4, stream);

    void* kargs[] = {(void*)&data,  (void*)&prop,   (void*)&W_ih,  (void*)&W_hh,
                     (void*)&b_ih,  (void*)&b_hh,   (void*)&W_cls, (void*)&b_cls,
                     (void*)&W_bbox, (void*)&b_bbox, (void*)&out,  (void*)&t0s,
                     (void*)&Hx32,  (void*)&cnt};
    hipLaunchCooperativeKernel((void*)fused_kernel, dim3(NSL * NGRP), dim3(1024),
                               kargs, 0, stream);
}

// Round 10
// 642.523 us; speedup vs baseline: 4.4949x; 1.2447x over previous
//
#include <hip/hip_runtime.h>
#include <math.h>

#define T_LEN 8192
#define NUM_CH 64
#define HID 256
#define NUM_CLS 40
#define NUM_PROP 1024
#define NUM_PROP_AFTER 256
#define PROP_LEN 128

#define MS 4        // sequences per group
#define NGRP 64     // sequence groups (NUM_PROP_AFTER / MS)
#define NSL 4       // hidden slices (64 units each)
#define KH 320      // K in halves: 256 h + 64 x
#define KSEGN 4     // K segments per row
#define SEGH 80     // halves per segment
#define HXPAR 65536 // u32s per parity buffer: 256 seqs x 256 units

typedef _Float16 h2_t __attribute__((ext_vector_type(2)));
union U32H2 { unsigned int u; h2_t h; };
union HU16 { _Float16 h; unsigned short u; };

#if defined(__has_builtin)
#if __has_builtin(__builtin_amdgcn_fdot2)
#define HAS_FDOT2 1
#endif
#endif

__device__ __forceinline__ float dot2f(unsigned int wa, unsigned int hb, float acc) {
    U32H2 a, b;
    a.u = wa;
    b.u = hb;
#ifdef HAS_FDOT2
    return __builtin_amdgcn_fdot2(a.h, b.h, acc, false);
#else
    return acc + (float)a.h[0] * (float)b.h[0] + (float)a.h[1] * (float)b.h[1];
#endif
}

__device__ __forceinline__ float dot8f(const uint4& w, const uint4& h, float acc) {
    acc = dot2f(w.x, h.x, acc);
    acc = dot2f(w.y, h.y, acc);
    acc = dot2f(w.z, h.z, acc);
    acc = dot2f(w.w, h.w, acc);
    return acc;
}

__device__ __forceinline__ float fsigmoid(float x) { return 1.0f / (1.0f + __expf(-x)); }
__device__ __forceinline__ float ftanh(float x) {
    float e = __expf(-2.0f * fabsf(x));
    float t = (1.0f - e) / (1.0f + e);
    return copysignf(t, x);
}

__device__ __forceinline__ unsigned int pack2(float a, float b) {
    HU16 ha, hb;
    ha.h = (_Float16)a;
    hb.h = (_Float16)b;
    return (unsigned int)ha.u | ((unsigned int)hb.u << 16);
}

// ---------------------------------------------------------------------------
// Fused cooperative kernel: 256 blocks (4 hid-slices x 64 seq-groups).
// EXACTLY the R5-verified structure (sound tagged-data exchange, 2 barriers,
// gather polling concurrent with producer reduce), with exchange width
// doubled: u64 paired publishes (128 stores) and u64 paired gathers
// (384 poll lanes, both embedded tags validated individually -- soundness
// identical to R5's per-u32 validation).
// ---------------------------------------------------------------------------
__global__ __launch_bounds__(1024, 4) void fused_kernel(
    const float* __restrict__ data, const float* __restrict__ prop,
    const float* __restrict__ W_ih, const float* __restrict__ W_hh,
    const float* __restrict__ b_ih, const float* __restrict__ b_hh,
    const float* __restrict__ W_cls, const float* __restrict__ b_cls,
    const float* __restrict__ W_bbox, const float* __restrict__ b_bbox,
    float* __restrict__ out, unsigned int* __restrict__ t0s,
    unsigned int* __restrict__ Hx32) {
    __shared__ __align__(16) _Float16 hx[MS][KH];       // 2.5 KB
    __shared__ __align__(16) float pp[MS][KSEGN][256];  // 16 KB (NMS overlay)

    const int tid = threadIdx.x;
    const int g = blockIdx.x & (NGRP - 1);
    const int s = blockIdx.x >> 6;
    const int kseg = tid >> 8;   // wave-uniform K segment
    const int rl = tid & 255;    // row_local = gate*64 + unit

    // ===================== block 0: NMS =====================
    if (blockIdx.x == 0) {
        float* sc_p = &pp[0][0][0];
        float* ss = &pp[1][0][0];
        float* se = &pp[2][0][0];
        unsigned char* sup = (unsigned char*)&pp[3][0][0];
        unsigned long long* cmask =
            (unsigned long long*)((char*)&pp[3][0][0] + 1024);

        float ps = prop[tid * 3 + 0];
        float pe = prop[tid * 3 + 1];
        float pc = prop[tid * 3 + 2];
        sc_p[tid] = pc;
        sup[tid] = 0;
        __syncthreads();

        int r = 0;
        for (int j = 0; j < NUM_PROP; ++j) {
            float o = sc_p[j];
            r += (o > pc) || (o == pc && j < tid);
        }
        ss[r] = ps;
        se[r] = pe;
        __syncthreads();

        const float my_s = ss[tid];
        const float my_e = se[tid];
        const float my_len = my_e - my_s;
        bool mysup = false;

        for (int ci = 0; ci < 16; ++ci) {
            if (tid < 64) {
                int i = ci * 64 + tid;
                float is_ = ss[i], ie_ = se[i];
                unsigned long long m = __ballot(sup[i] != 0);
                for (int l = 0; l < 64; ++l) {
                    if (!((m >> l) & 1)) {
                        float ls = __shfl(is_, l);
                        float le = __shfl(ie_, l);
                        float inter = fmaxf(fminf(le, ie_) - fmaxf(ls, is_), 0.0f);
                        float uni = (le - ls) + (ie_ - is_) - inter;
                        float iou = inter / fmaxf(uni, 1e-6f);
                        unsigned long long nb = __ballot((tid > l) && (iou > 0.5f));
                        m |= nb;
                    }
                }
                sup[i] = (unsigned char)((m >> tid) & 1);
                if (tid == 0) cmask[ci] = ~m;
            }
            __syncthreads();
            unsigned long long am = cmask[ci];
            for (int l = 0; l < 64; ++l) {
                if ((am >> l) & 1) {
                    int i = ci * 64 + l;
                    if (tid > i && !mysup) {
                        float ls = ss[i], le = se[i];
                        float inter = fmaxf(fminf(le, my_e) - fmaxf(ls, my_s), 0.0f);
                        float uni = (le - ls) + my_len - inter;
                        if (inter / fmaxf(uni, 1e-6f) > 0.5f) mysup = true;
                    }
                }
            }
            sup[tid] = mysup ? 1 : 0;
            __syncthreads();
        }

        int myc = tid >> 6;
        unsigned long long mybit = 1ull << (tid & 63);
        int kb = 0, kt = 0;
        for (int c2 = 0; c2 < 16; ++c2) {
            int p = __popcll(cmask[c2]);
            kt += p;
            if (c2 < myc) kb += p;
        }
        kb += __popcll(cmask[myc] & (mybit - 1));
        int slot = (cmask[myc] & mybit) ? kb : (kt + (tid - kb));
        if (slot < NUM_PROP_AFTER) {
            int t0v = (int)rintf(my_s);
            t0v = max(0, min(t0v, T_LEN - PROP_LEN));
            __hip_atomic_store(&t0s[slot], (unsigned int)t0v | 0x80000000u,
                               __ATOMIC_RELAXED, __HIP_MEMORY_SCOPE_AGENT);
        }
        asm volatile("s_waitcnt vmcnt(0)" ::: "memory");
        __syncthreads();
    }

    // ============ W fragment: direct f32 load + f16 pack ============
    uint4 Wr[10];
    {
        const int gate = rl >> 6, unit = rl & 63;
        const int grow = gate * 256 + s * 64 + unit;
        const float* __restrict__ baseh = W_hh + grow * HID;
        const float* __restrict__ basex = W_ih + grow * NUM_CH;
#pragma unroll
        for (int j = 0; j < 10; ++j) {
            const int kh = kseg * SEGH + j * 8;
            const float* src = (kh < 256) ? (baseh + kh) : (basex + (kh - 256));
            float4 f0 = *(const float4*)(src);
            float4 f1 = *(const float4*)(src + 4);
            Wr[j] = make_uint4(pack2(f0.x, f0.y), pack2(f0.z, f0.w),
                               pack2(f1.x, f1.y), pack2(f1.z, f1.w));
        }
    }

    // producer role (tid<256): wave aq = seq, lane au = unit of slice s
    const int aq = tid >> 6;
    const int au = tid & 63;
    float bi = 0.f, bf = 0.f, bg = 0.f, bo = 0.f, c_st = 0.f;
    int xt0 = 0;
    if (tid < 256) {
        int u = s * 64 + au;
        bi = b_ih[u] + b_hh[u];
        bf = b_ih[256 + u] + b_hh[256 + u];
        bg = b_ih[512 + u] + b_hh[512 + u];
        bo = b_ih[768 + u] + b_hh[768 + u];
    }

    // gather role (tid 256..639): 384 lanes, each one u64 = 2 tagged words.
    // lane li: peer gp (0..2), seq gsq2, even unit gu2.
    const int li = tid - 256;                 // 0..383 (valid when tid<640)
    const int gp = li >> 7;                   // peer index
    const int rem = li & 127;
    const int gsq2 = rem >> 5;                // seq
    const int gu2 = (rem & 31) * 2;           // even unit
    const int sp2 = gp + (gp >= s ? 1 : 0);   // peer slice
    const int goff = (g * MS + gsq2) * HID + sp2 * 64 + gu2;  // u32 index (even)

    // zero h region of hx
    hx[tid >> 8][tid & 255] = (_Float16)0.0f;

    // producers poll tagged t0s (64 lanes same addr, s_sleep backoff), load x(0)
    if (tid < 256) {
        const unsigned int* tp = &t0s[g * MS + aq];
        unsigned int tv;
        for (;;) {
            tv = __hip_atomic_load(tp, __ATOMIC_RELAXED, __HIP_MEMORY_SCOPE_AGENT);
            if (tv & 0x80000000u) break;
            __builtin_amdgcn_s_sleep(8);
        }
        xt0 = (int)(tv & 0x7FFFFFFFu);
        hx[aq][256 + au] = (_Float16)data[xt0 * NUM_CH + au];  // x(0)
    }
    __syncthreads();

    for (int t = 0; t < PROP_LEN; ++t) {
        // producers: issue x(t+1) load EARLY (consumed after the dot; HBM
        // latency hides under the ~1.3us dot)
        float xnext = 0.0f;
        if (tid < 256 && t + 1 < PROP_LEN)
            xnext = data[(xt0 + t + 1) * NUM_CH + au];

        // --- dot: 4 accumulator chains, broadcast LDS reads ---
        float a0 = 0.f, a1 = 0.f, a2 = 0.f, a3 = 0.f;
#pragma unroll
        for (int j = 0; j < 10; ++j) {
            const int hb = kseg * SEGH + j * 8;
            uint4 h0 = *(const uint4*)&hx[0][hb];
            uint4 h1 = *(const uint4*)&hx[1][hb];
            uint4 h2 = *(const uint4*)&hx[2][hb];
            uint4 h3 = *(const uint4*)&hx[3][hb];
            uint4 w = Wr[j];
            a0 = dot8f(w, h0, a0);
            a1 = dot8f(w, h1, a1);
            a2 = dot8f(w, h2, a2);
            a3 = dot8f(w, h3, a3);
        }
        pp[0][kseg][rl] = a0;
        pp[1][kseg][rl] = a1;
        pp[2][kseg][rl] = a2;
        pp[3][kseg][rl] = a3;
        __syncthreads();  // B1

        const unsigned int tagv = (unsigned int)(t + 1);
        const int par = (t + 1) & 1;
        if (tid < 256) {
            // --- reduce + activation + PAIRED tagged publish ---
            float si = pp[aq][0][au] + pp[aq][1][au] + pp[aq][2][au] +
                       pp[aq][3][au] + bi;
            float sf = pp[aq][0][64 + au] + pp[aq][1][64 + au] +
                       pp[aq][2][64 + au] + pp[aq][3][64 + au] + bf;
            float sg = pp[aq][0][128 + au] + pp[aq][1][128 + au] +
                       pp[aq][2][128 + au] + pp[aq][3][128 + au] + bg;
            float so = pp[aq][0][192 + au] + pp[aq][1][192 + au] +
                       pp[aq][2][192 + au] + pp[aq][3][192 + au] + bo;
            float gi = fsigmoid(si), gf = fsigmoid(sf);
            float gg = ftanh(sg), go = fsigmoid(so);
            c_st = gf * c_st + gi * gg;
            float h = go * ftanh(c_st);
            HU16 hu;
            hu.h = (_Float16)h;
            unsigned int myw = (tagv << 16) | (unsigned int)hu.u;
            unsigned int pw = __shfl_xor(myw, 1);  // partner lane's word
            if ((au & 1) == 0) {
                unsigned long long dw =
                    (unsigned long long)myw | ((unsigned long long)pw << 32);
                __hip_atomic_store(
                    (unsigned long long*)&Hx32[par * HXPAR +
                                               (g * MS + aq) * HID + s * 64 + au],
                    dw, __ATOMIC_RELAXED, __HIP_MEMORY_SCOPE_AGENT);
            }
            hx[aq][s * 64 + au] = hu.h;                       // own slice -> LDS
            if (t + 1 < PROP_LEN) hx[aq][256 + au] = (_Float16)xnext;  // x(t+1)
        } else if (tid < 640) {
            // --- paired gather; BOTH embedded tags validated (soundness as R5) ---
            const unsigned long long* ga =
                (const unsigned long long*)(Hx32 + par * HXPAR + goff);
            unsigned long long v =
                __hip_atomic_load(ga, __ATOMIC_RELAXED, __HIP_MEMORY_SCOPE_AGENT);
            while (__builtin_expect(((unsigned int)v >> 16) != tagv ||
                                        ((unsigned int)(v >> 32) >> 16) != tagv,
                                    0)) {
                __builtin_amdgcn_s_sleep(1);
                v = __hip_atomic_load(ga, __ATOMIC_RELAXED,
                                      __HIP_MEMORY_SCOPE_AGENT);
            }
            unsigned int lo = (unsigned int)v;
            unsigned int hi = (unsigned int)(v >> 32);
            unsigned int packed = (lo & 0xFFFFu) | (hi << 16);  // 2 f16 halves
            *(unsigned int*)&hx[gsq2][sp2 * 64 + gu2] = packed;
        }
        __syncthreads();  // B2
    }

    // hx holds h_128 for all 4 seqs. Slice s computes rows [30s, 30s+30).
    if (tid < MS * 30) {
        int sq = tid / 30;
        int ml = tid % 30;
        int m = s * 30 + ml;
        const float* Wrow;
        float acc;
        int oidx;
        if (m < NUM_CLS) {
            Wrow = W_cls + m * HID;
            acc = b_cls[m];
            oidx = (g * MS + sq) * NUM_CLS + m;
        } else {
            int mb = m - NUM_CLS;
            Wrow = W_bbox + mb * HID;
            acc = b_bbox[mb];
            oidx = NUM_PROP_AFTER * NUM_CLS + (g * MS + sq) * 2 * NUM_CLS + mb;
        }
        const float4* w4 = (const float4*)Wrow;
        const _Float16* hp = &hx[sq][0];
        for (int c = 0; c < 32; ++c) {
            float4 wa = w4[c * 2 + 0];
            float4 wb = w4[c * 2 + 1];
            acc += (float)hp[c * 8 + 0] * wa.x + (float)hp[c * 8 + 1] * wa.y +
                   (float)hp[c * 8 + 2] * wa.z + (float)hp[c * 8 + 3] * wa.w +
                   (float)hp[c * 8 + 4] * wb.x + (float)hp[c * 8 + 5] * wb.y +
                   (float)hp[c * 8 + 6] * wb.z + (float)hp[c * 8 + 7] * wb.w;
        }
        out[oidx] = acc;
    }
}

extern "C" void kernel_launch(void* const* d_in, const int* in_sizes, int n_in,
                              void* d_out, int out_size, void* d_ws,
                              size_t ws_size, hipStream_t stream) {
    const float* data = (const float*)d_in[0];     // [8192, 64]
    const float* prop = (const float*)d_in[1];     // [1024, 3]
    const float* W_ih = (const float*)d_in[2];     // [1024, 64]
    const float* W_hh = (const float*)d_in[3];     // [1024, 256]
    const float* b_ih = (const float*)d_in[4];     // [1024]
    const float* b_hh = (const float*)d_in[5];     // [1024]
    const float* W_cls = (const float*)d_in[6];    // [40, 256]
    const float* b_cls = (const float*)d_in[7];    // [40]
    const float* W_bbox = (const float*)d_in[8];   // [80, 256]
    const float* b_bbox = (const float*)d_in[9];   // [80]
    float* out = (float*)d_out;

    // workspace layout (identical to R5)
    unsigned int* t0s = (unsigned int*)d_ws;                   // [0, 1KB) tagged t0s
    unsigned int* Hx32 = (unsigned int*)((char*)d_ws + 4096);  // 512 KB tagged h (2 parities)

    // zero all tags each invocation (graph-captured, replayed per rep)
    hipMemsetAsync(d_ws, 0, 4096 + 2 * HXPAR * 4, stream);

    void* kargs[] = {(void*)&data,  (void*)&prop,   (void*)&W_ih,  (void*)&W_hh,
                     (void*)&b_ih,  (void*)&b_hh,   (void*)&W_cls, (void*)&b_cls,
                     (void*)&W_bbox, (void*)&b_bbox, (void*)&out,  (void*)&t0s,
                     (void*)&Hx32};
    hipLaunchCooperativeKernel((void*)fused_kernel, dim3(NSL * NGRP), dim3(1024),
                               kargs, 0, stream);
}

// Round 11
// 628.212 us; speedup vs baseline: 4.5973x; 1.0228x over previous
//
#include <hip/hip_runtime.h>
#include <math.h>

#define T_LEN 8192
#define NUM_CH 64
#define HID 256
#define NUM_CLS 40
#define NUM_PROP 1024
#define NUM_PROP_AFTER 256
#define PROP_LEN 128

#define MS 4        // sequences per group
#define NGRP 64     // sequence groups (NUM_PROP_AFTER / MS)
#define NSL 4       // hidden slices (64 units each)
#define KH 320      // block-local kappa: [0,64) own-h, [64,128) x, [128,320) peer-h
#define KSEGN 4     // K segments per row
#define SEGH 80     // halves per segment
#define HXPAR 65536 // u32s per parity buffer: 256 seqs x 256 units

typedef _Float16 h2_t __attribute__((ext_vector_type(2)));
union U32H2 { unsigned int u; h2_t h; };
union HU16 { _Float16 h; unsigned short u; };

#if defined(__has_builtin)
#if __has_builtin(__builtin_amdgcn_fdot2)
#define HAS_FDOT2 1
#endif
#endif

__device__ __forceinline__ float dot2f(unsigned int wa, unsigned int hb, float acc) {
    U32H2 a, b;
    a.u = wa;
    b.u = hb;
#ifdef HAS_FDOT2
    return __builtin_amdgcn_fdot2(a.h, b.h, acc, false);
#else
    return acc + (float)a.h[0] * (float)b.h[0] + (float)a.h[1] * (float)b.h[1];
#endif
}

__device__ __forceinline__ float dot8f(const uint4& w, const uint4& h, float acc) {
    acc = dot2f(w.x, h.x, acc);
    acc = dot2f(w.y, h.y, acc);
    acc = dot2f(w.z, h.z, acc);
    acc = dot2f(w.w, h.w, acc);
    return acc;
}

__device__ __forceinline__ float fsigmoid(float x) { return 1.0f / (1.0f + __expf(-x)); }
__device__ __forceinline__ float ftanh(float x) {
    float e = __expf(-2.0f * fabsf(x));
    float t = (1.0f - e) / (1.0f + e);
    return copysignf(t, x);
}

__device__ __forceinline__ unsigned int pack2(float a, float b) {
    HU16 ha, hb;
    ha.h = (_Float16)a;
    hb.h = (_Float16)b;
    return (unsigned int)ha.u | ((unsigned int)hb.u << 16);
}

// ---------------------------------------------------------------------------
// R10 base (tagged u64 exchange, verified) + split-dot overlap:
// kappa-reordered W so kseg0 (waves 0-3) is fully LOCAL (own-h + x) and
// kseg1 is 60% local; waves 8-13 gather peer h(t) CONCURRENTLY with the
// local dots (publish happened at prev W2, ~0.1us earlier -> few retries);
// peer-dots gated by intra-CU LDS flags (R7-verified mechanism, now without
// R7's VGPR spill: Wr[10]=40 regs).  2 barriers/step unchanged.
// ---------------------------------------------------------------------------
__global__ __launch_bounds__(1024, 4) void fused_kernel(
    const float* __restrict__ data, const float* __restrict__ prop,
    const float* __restrict__ W_ih, const float* __restrict__ W_hh,
    const float* __restrict__ b_ih, const float* __restrict__ b_hh,
    const float* __restrict__ W_cls, const float* __restrict__ b_cls,
    const float* __restrict__ W_bbox, const float* __restrict__ b_bbox,
    float* __restrict__ out, unsigned int* __restrict__ t0s,
    unsigned int* __restrict__ Hx32) {
    __shared__ __align__(16) _Float16 hx[MS][KH];       // 2.5 KB (kappa layout)
    __shared__ __align__(16) float pp[MS][KSEGN][256];  // 16 KB (NMS overlay)
    __shared__ volatile unsigned int gfl[6];            // gather-wave flags

    const int tid = threadIdx.x;
    const int g = blockIdx.x & (NGRP - 1);
    const int s = blockIdx.x >> 6;
    const int kseg = tid >> 8;   // wave-uniform K segment
    const int rl = tid & 255;    // row_local = gate*64 + unit

    // ===================== block 0: NMS =====================
    if (blockIdx.x == 0) {
        float* sc_p = &pp[0][0][0];
        float* ss = &pp[1][0][0];
        float* se = &pp[2][0][0];
        unsigned char* sup = (unsigned char*)&pp[3][0][0];
        unsigned long long* cmask =
            (unsigned long long*)((char*)&pp[3][0][0] + 1024);

        float ps = prop[tid * 3 + 0];
        float pe = prop[tid * 3 + 1];
        float pc = prop[tid * 3 + 2];
        sc_p[tid] = pc;
        sup[tid] = 0;
        __syncthreads();

        int r = 0;
        for (int j = 0; j < NUM_PROP; ++j) {
            float o = sc_p[j];
            r += (o > pc) || (o == pc && j < tid);
        }
        ss[r] = ps;
        se[r] = pe;
        __syncthreads();

        const float my_s = ss[tid];
        const float my_e = se[tid];
        const float my_len = my_e - my_s;
        bool mysup = false;

        for (int ci = 0; ci < 16; ++ci) {
            if (tid < 64) {
                int i = ci * 64 + tid;
                float is_ = ss[i], ie_ = se[i];
                unsigned long long m = __ballot(sup[i] != 0);
                for (int l = 0; l < 64; ++l) {
                    if (!((m >> l) & 1)) {
                        float ls = __shfl(is_, l);
                        float le = __shfl(ie_, l);
                        float inter = fmaxf(fminf(le, ie_) - fmaxf(ls, is_), 0.0f);
                        float uni = (le - ls) + (ie_ - is_) - inter;
                        float iou = inter / fmaxf(uni, 1e-6f);
                        unsigned long long nb = __ballot((tid > l) && (iou > 0.5f));
                        m |= nb;
                    }
                }
                sup[i] = (unsigned char)((m >> tid) & 1);
                if (tid == 0) cmask[ci] = ~m;
            }
            __syncthreads();
            unsigned long long am = cmask[ci];
            for (int l = 0; l < 64; ++l) {
                if ((am >> l) & 1) {
                    int i = ci * 64 + l;
                    if (tid > i && !mysup) {
                        float ls = ss[i], le = se[i];
                        float inter = fmaxf(fminf(le, my_e) - fmaxf(ls, my_s), 0.0f);
                        float uni = (le - ls) + my_len - inter;
                        if (inter / fmaxf(uni, 1e-6f) > 0.5f) mysup = true;
                    }
                }
            }
            sup[tid] = mysup ? 1 : 0;
            __syncthreads();
        }

        int myc = tid >> 6;
        unsigned long long mybit = 1ull << (tid & 63);
        int kb = 0, kt = 0;
        for (int c2 = 0; c2 < 16; ++c2) {
            int p = __popcll(cmask[c2]);
            kt += p;
            if (c2 < myc) kb += p;
        }
        kb += __popcll(cmask[myc] & (mybit - 1));
        int slot = (cmask[myc] & mybit) ? kb : (kt + (tid - kb));
        if (slot < NUM_PROP_AFTER) {
            int t0v = (int)rintf(my_s);
            t0v = max(0, min(t0v, T_LEN - PROP_LEN));
            __hip_atomic_store(&t0s[slot], (unsigned int)t0v | 0x80000000u,
                               __ATOMIC_RELAXED, __HIP_MEMORY_SCOPE_AGENT);
        }
        asm volatile("s_waitcnt vmcnt(0)" ::: "memory");
        __syncthreads();
    }

    // ===== W fragment in kappa order: Wr[10] = 80 halves of row (s,rl) =====
    uint4 Wr[10];
    {
        const int gate = rl >> 6, unit = rl & 63;
        const int grow = gate * 256 + s * 64 + unit;
        const float* __restrict__ bh = W_hh + grow * HID;
        const float* __restrict__ bx = W_ih + grow * NUM_CH;
#pragma unroll
        for (int j = 0; j < 10; ++j) {
            const int kp = kseg * SEGH + j * 8;  // kappa
            const float* src;
            if (kp < 64) {
                src = bh + s * 64 + kp;                     // own-slice h
            } else if (kp < 128) {
                src = bx + (kp - 64);                       // x
            } else {
                int q = (kp - 128) >> 6, v = (kp - 128) & 63;
                int sp = q + (q >= s ? 1 : 0);
                src = bh + sp * 64 + v;                     // peer-slice h
            }
            float4 f0 = *(const float4*)src;
            float4 f1 = *(const float4*)(src + 4);
            Wr[j] = make_uint4(pack2(f0.x, f0.y), pack2(f0.z, f0.w),
                               pack2(f1.x, f1.y), pack2(f1.z, f1.w));
        }
    }

    // producer role (tid<256): wave aq = seq, lane au = unit of slice s
    const int aq = tid >> 6;
    const int au = tid & 63;
    float bi = 0.f, bf = 0.f, bg = 0.f, bo = 0.f, c_st = 0.f;
    int xt0 = 0;
    if (tid < 256) {
        int u = s * 64 + au;
        bi = b_ih[u] + b_hh[u];
        bf = b_ih[256 + u] + b_hh[256 + u];
        bg = b_ih[512 + u] + b_hh[512 + u];
        bo = b_ih[768 + u] + b_hh[768 + u];
    }

    // gather role (waves 8-13, tid 512..895): lane li, one u64 = 2 tagged words
    const int li = tid - 512;                 // 0..383
    const int q_ = li >> 7;                   // peer index 0..2
    const int rem = li & 127;
    const int gsq = rem >> 5;                 // seq
    const int gu2 = (rem & 31) * 2;           // even unit within peer slice
    const int sp_ = q_ + (q_ >= s ? 1 : 0);   // peer slice
    const int goff = (g * MS + gsq) * HID + sp_ * 64 + gu2;  // even u32 index
    const int gw = (tid >> 6) - 8;            // gather wave id 0..5

    // zero hx (1280 halves) + flags
    ((unsigned short*)hx)[tid] = 0;
    if (tid < 256) ((unsigned short*)hx)[1024 + tid] = 0;
    if (tid < 6) gfl[tid] = 0;

    // producers poll tagged t0s, load x(0) -> kappa [64,128)
    if (tid < 256) {
        const unsigned int* tp = &t0s[g * MS + aq];
        unsigned int tv;
        for (;;) {
            tv = __hip_atomic_load(tp, __ATOMIC_RELAXED, __HIP_MEMORY_SCOPE_AGENT);
            if (tv & 0x80000000u) break;
            __builtin_amdgcn_s_sleep(8);
        }
        xt0 = (int)(tv & 0x7FFFFFFFu);
        hx[aq][64 + au] = (_Float16)data[xt0 * NUM_CH + au];  // x(0)
    }
    __syncthreads();

    for (int t = 0; t < PROP_LEN; ++t) {
        // producers: early x(t+1) issue (lands during the dot)
        float xnext = 0.0f;
        if (tid < 256 && t + 1 < PROP_LEN)
            xnext = data[(xt0 + t + 1) * NUM_CH + au];

        float a0 = 0.f, a1 = 0.f, a2 = 0.f, a3 = 0.f;
#define DOTJ(J)                                                         \
        {                                                               \
            const int hb = kseg * SEGH + (J) * 8;                       \
            uint4 h0 = *(const uint4*)&hx[0][hb];                       \
            uint4 h1 = *(const uint4*)&hx[1][hb];                       \
            uint4 h2 = *(const uint4*)&hx[2][hb];                       \
            uint4 h3 = *(const uint4*)&hx[3][hb];                       \
            uint4 w = Wr[(J)];                                          \
            a0 = dot8f(w, h0, a0);                                      \
            a1 = dot8f(w, h1, a1);                                      \
            a2 = dot8f(w, h2, a2);                                      \
            a3 = dot8f(w, h3, a3);                                      \
        }

        // --- phase 1: local dot (kseg0: all 10; kseg1: first 6) ---
        if (kseg == 0) {
            DOTJ(0) DOTJ(1) DOTJ(2) DOTJ(3) DOTJ(4)
            DOTJ(5) DOTJ(6) DOTJ(7) DOTJ(8) DOTJ(9)
        } else if (kseg == 1) {
            DOTJ(0) DOTJ(1) DOTJ(2) DOTJ(3) DOTJ(4) DOTJ(5)
        }

        // --- gather peer h(t) (waves 8-13), concurrent with local dots ---
        if (t >= 1 && tid >= 512 && tid < 896) {
            const unsigned int tagv = (unsigned int)t;
            const int par = t & 1;
            const unsigned long long* ga =
                (const unsigned long long*)(Hx32 + par * HXPAR + goff);
            unsigned long long v =
                __hip_atomic_load(ga, __ATOMIC_RELAXED, __HIP_MEMORY_SCOPE_AGENT);
            while (__builtin_expect(((unsigned int)v >> 16) != tagv ||
                                        ((unsigned int)(v >> 32) >> 16) != tagv,
                                    0)) {
                __builtin_amdgcn_s_sleep(2);
                v = __hip_atomic_load(ga, __ATOMIC_RELAXED,
                                      __HIP_MEMORY_SCOPE_AGENT);
            }
            unsigned int lo = (unsigned int)v;
            unsigned int hi = (unsigned int)(v >> 32);
            *(unsigned int*)&hx[gsq][128 + q_ * 64 + gu2] =
                (lo & 0xFFFFu) | (hi << 16);
            asm volatile("s_waitcnt lgkmcnt(0)" ::: "memory");
            if ((tid & 63) == 0) gfl[gw] = (unsigned int)t;
        }

        // --- flag wait, then peer dot (kseg >= 1) ---
        if (kseg != 0) {
            if (t >= 1) {
                while (gfl[0] < (unsigned int)t || gfl[1] < (unsigned int)t ||
                       gfl[2] < (unsigned int)t || gfl[3] < (unsigned int)t ||
                       gfl[4] < (unsigned int)t || gfl[5] < (unsigned int)t) {
                    __builtin_amdgcn_s_sleep(1);
                }
                asm volatile("" ::: "memory");
            }
            if (kseg == 1) {
                DOTJ(6) DOTJ(7) DOTJ(8) DOTJ(9)
            } else {
                DOTJ(0) DOTJ(1) DOTJ(2) DOTJ(3) DOTJ(4)
                DOTJ(5) DOTJ(6) DOTJ(7) DOTJ(8) DOTJ(9)
            }
        }
#undef DOTJ

        pp[0][kseg][rl] = a0;
        pp[1][kseg][rl] = a1;
        pp[2][kseg][rl] = a2;
        pp[3][kseg][rl] = a3;
        __syncthreads();  // B1

        const unsigned int tagv = (unsigned int)(t + 1);
        const int par = (t + 1) & 1;
        if (tid < 256) {
            // --- reduce + activation + PAIRED tagged publish + local writes ---
            float si = pp[aq][0][au] + pp[aq][1][au] + pp[aq][2][au] +
                       pp[aq][3][au] + bi;
            float sf = pp[aq][0][64 + au] + pp[aq][1][64 + au] +
                       pp[aq][2][64 + au] + pp[aq][3][64 + au] + bf;
            float sg = pp[aq][0][128 + au] + pp[aq][1][128 + au] +
                       pp[aq][2][128 + au] + pp[aq][3][128 + au] + bg;
            float so = pp[aq][0][192 + au] + pp[aq][1][192 + au] +
                       pp[aq][2][192 + au] + pp[aq][3][192 + au] + bo;
            float gi = fsigmoid(si), gf = fsigmoid(sf);
            float gg = ftanh(sg), go = fsigmoid(so);
            c_st = gf * c_st + gi * gg;
            float h = go * ftanh(c_st);
            HU16 hu;
            hu.h = (_Float16)h;
            unsigned int myw = (tagv << 16) | (unsigned int)hu.u;
            unsigned int pw = __shfl_xor(myw, 1);
            if ((au & 1) == 0) {
                unsigned long long dw =
                    (unsigned long long)myw | ((unsigned long long)pw << 32);
                __hip_atomic_store(
                    (unsigned long long*)&Hx32[par * HXPAR +
                                               (g * MS + aq) * HID + s * 64 + au],
                    dw, __ATOMIC_RELAXED, __HIP_MEMORY_SCOPE_AGENT);
            }
            hx[aq][au] = hu.h;                                  // own-h, kappa [0,64)
            if (t + 1 < PROP_LEN) hx[aq][64 + au] = (_Float16)xnext;  // x(t+1)
        }
        __syncthreads();  // B2
    }

    // final gather: peer h(128) (tag 128, parity 0) for the heads
    if (tid >= 512 && tid < 896) {
        const unsigned int tagv = (unsigned int)PROP_LEN;
        const unsigned long long* ga = (const unsigned long long*)(Hx32 + goff);
        unsigned long long v =
            __hip_atomic_load(ga, __ATOMIC_RELAXED, __HIP_MEMORY_SCOPE_AGENT);
        while (((unsigned int)v >> 16) != tagv ||
               ((unsigned int)(v >> 32) >> 16) != tagv) {
            __builtin_amdgcn_s_sleep(2);
            v = __hip_atomic_load(ga, __ATOMIC_RELAXED, __HIP_MEMORY_SCOPE_AGENT);
        }
        unsigned int lo = (unsigned int)v;
        unsigned int hi = (unsigned int)(v >> 32);
        *(unsigned int*)&hx[gsq][128 + q_ * 64 + gu2] = (lo & 0xFFFFu) | (hi << 16);
    }
    __syncthreads();

    // heads: hx kappa layout: own [0,64), peers q at [128+q*64, ...)
    if (tid < MS * 30) {
        int sq = tid / 30;
        int ml = tid % 30;
        int m = s * 30 + ml;
        const float* Wrow;
        float acc;
        int oidx;
        if (m < NUM_CLS) {
            Wrow = W_cls + m * HID;
            acc = b_cls[m];
            oidx = (g * MS + sq) * NUM_CLS + m;
        } else {
            int mb = m - NUM_CLS;
            Wrow = W_bbox + mb * HID;
            acc = b_bbox[mb];
            oidx = NUM_PROP_AFTER * NUM_CLS + (g * MS + sq) * 2 * NUM_CLS + mb;
        }
        const _Float16* hp = &hx[sq][0];
        for (int k = 0; k < 64; ++k) acc += Wrow[s * 64 + k] * (float)hp[k];
        for (int q2 = 0; q2 < 3; ++q2) {
            int sp2 = q2 + (q2 >= s ? 1 : 0);
            const float* wr = Wrow + sp2 * 64;
            const _Float16* hr = hp + 128 + q2 * 64;
            for (int v2 = 0; v2 < 64; ++v2) acc += wr[v2] * (float)hr[v2];
        }
        out[oidx] = acc;
    }
}

extern "C" void kernel_launch(void* const* d_in, const int* in_sizes, int n_in,
                              void* d_out, int out_size, void* d_ws,
                              size_t ws_size, hipStream_t stream) {
    const float* data = (const float*)d_in[0];     // [8192, 64]
    const float* prop = (const float*)d_in[1];     // [1024, 3]
    const float* W_ih = (const float*)d_in[2];     // [1024, 64]
    const float* W_hh = (const float*)d_in[3];     // [1024, 256]
    const float* b_ih = (const float*)d_in[4];     // [1024]
    const float* b_hh = (const float*)d_in[5];     // [1024]
    const float* W_cls = (const float*)d_in[6];    // [40, 256]
    const float* b_cls = (const float*)d_in[7];    // [40]
    const float* W_bbox = (const float*)d_in[8];   // [80, 256]
    const float* b_bbox = (const float*)d_in[9];   // [80]
    float* out = (float*)d_out;

    // workspace layout (identical to R10)
    unsigned int* t0s = (unsigned int*)d_ws;                   // [0, 1KB) tagged t0s
    unsigned int* Hx32 = (unsigned int*)((char*)d_ws + 4096);  // 512 KB tagged h (2 parities)

    // zero all tags each invocation (graph-captured, replayed per rep)
    hipMemsetAsync(d_ws, 0, 4096 + 2 * HXPAR * 4, stream);

    void* kargs[] = {(void*)&data,  (void*)&prop,   (void*)&W_ih,  (void*)&W_hh,
                     (void*)&b_ih,  (void*)&b_hh,   (void*)&W_cls, (void*)&b_cls,
                     (void*)&W_bbox, (void*)&b_bbox, (void*)&out,  (void*)&t0s,
                     (void*)&Hx32};
    hipLaunchCooperativeKernel((void*)fused_kernel, dim3(NSL * NGRP), dim3(1024),
                               kargs, 0, stream);
}